// Round 2
// baseline (205.301 us; speedup 1.0000x reference)
//
#include <hip/hip_runtime.h>
#include <math.h>

typedef __attribute__((ext_vector_type(4))) float  floatx4;
typedef __attribute__((ext_vector_type(16))) float f32x16;
typedef __attribute__((ext_vector_type(8))) short  short8;
typedef __attribute__((ext_vector_type(4))) short  short4v;
typedef __attribute__((ext_vector_type(8))) __bf16 bf16x8;
typedef __attribute__((ext_vector_type(4))) unsigned int uint4v;

#define E_DIM 768
#define T_DIM 2048
#define N_B   2
#define N_H   12
#define H_D   64
#define M_TOT 4096  /* N_B * T_DIM */

// 0.125 * log2(e): folded into Q so exp2() applies directly to QK^T output
#define Q_SCALE 0.1803368801111204f

#if __has_builtin(__builtin_amdgcn_exp2f)
#define EXP2F(x) __builtin_amdgcn_exp2f(x)
#else
#define EXP2F(x) exp2f(x)
#endif
#if __has_builtin(__builtin_amdgcn_rcpf)
#define RCPF(x) __builtin_amdgcn_rcpf(x)
#else
#define RCPF(x) (1.0f / (x))
#endif

__device__ __forceinline__ unsigned short f32_to_bf16(float f) {
  unsigned int u = __float_as_uint(f);
  u += 0x7fffu + ((u >> 16) & 1u);
  return (unsigned short)(u >> 16);
}

// barrier that waits LDS only (no vmcnt drain -> global prefetch stays in flight)
__device__ __forceinline__ void lds_barrier() {
  asm volatile("s_waitcnt lgkmcnt(0)\n\ts_barrier" ::: "memory");
}

__device__ __forceinline__ void gload_lds16(const unsigned short* g, unsigned short* l) {
  __builtin_amdgcn_global_load_lds(
      (const __attribute__((address_space(1))) unsigned int*)(const void*)g,
      (__attribute__((address_space(3))) unsigned int*)(void*)l, 16, 0, 0);
}

// v_cvt_pk_bf16_f32: low16 = bf16(lo), high16 = bf16(hi)  (no builtin on gfx950)
__device__ __forceinline__ unsigned int cvtpk_bf16(float lo, float hi) {
  unsigned int r;
  asm("v_cvt_pk_bf16_f32 %0, %1, %2" : "=v"(r) : "v"(lo), "v"(hi));
  return r;
}

// v_permlane32_swap_b32 D, S: exchanges the UPPER half of D with the LOWER half of S:
//   D[l>=32] <- S_old[l-32] ; S[l<32] <- D_old[l+32] ; D[l<32], S[l>=32] unchanged.
// Call as perml32_swap(low_pairs, high_pairs).
__device__ __forceinline__ void perml32_swap(unsigned int& a, unsigned int& b) {
  asm volatile("v_permlane32_swap_b32 %0, %1" : "+v"(a), "+v"(b));
}

// ---- input convert: Xb[z][m][k] = bf16(x[m][k]) ----
__global__ __launch_bounds__(256) void convert_x(const float* __restrict__ q,
                                                 const float* __restrict__ k,
                                                 const float* __restrict__ v,
                                                 unsigned short* __restrict__ Xb) {
  const int z = blockIdx.y;
  const float* src = (z == 0) ? q : (z == 1) ? k : v;
  size_t idx = ((size_t)blockIdx.x * 256 + threadIdx.x) * 4;
  float4 val = *reinterpret_cast<const float4*>(&src[idx]);
  short4v o;
  o[0] = (short)f32_to_bf16(val.x);
  o[1] = (short)f32_to_bf16(val.y);
  o[2] = (short)f32_to_bf16(val.z);
  o[3] = (short)f32_to_bf16(val.w);
  *reinterpret_cast<short4v*>(&Xb[(size_t)z * M_TOT * E_DIM + idx]) = o;
}

// ---- weight convert+transpose (all 4 weights, one launch): Wt[z][n][k] = bf16(W[z][k][n]) ----
__global__ __launch_bounds__(256) void transpose_w4(const float* __restrict__ W0,
                                                    const float* __restrict__ W1,
                                                    const float* __restrict__ W2,
                                                    const float* __restrict__ W3,
                                                    unsigned short* __restrict__ Wt) {
  __shared__ float tile[32][33];
  const int z = blockIdx.z;
  const float* W = (z == 0) ? W0 : (z == 1) ? W1 : (z == 2) ? W2 : W3;
  unsigned short* dst = Wt + (size_t)z * E_DIM * E_DIM;
  int k0 = blockIdx.x * 32, n0 = blockIdx.y * 32;
  int tx = threadIdx.x & 31, ty = threadIdx.x >> 5;
  for (int i = 0; i < 4; i++)
    tile[ty + i * 8][tx] = W[(size_t)(k0 + ty + i * 8) * E_DIM + n0 + tx];
  __syncthreads();
  for (int i = 0; i < 4; i++)
    dst[(size_t)(n0 + ty + i * 8) * E_DIM + k0 + tx] = f32_to_bf16(tile[tx][ty + i * 8]);
}

// ---- QKV projection (m97-style global_load_lds staging) ----
__global__ __launch_bounds__(256) void gemm_qkv(const unsigned short* __restrict__ Xb,
                                                const unsigned short* __restrict__ WtAll,
                                                const float* __restrict__ bq,
                                                const float* __restrict__ bk,
                                                const float* __restrict__ bv,
                                                unsigned short* __restrict__ outQKV) {
  __shared__ unsigned short As[128 * 32];
  __shared__ unsigned short Bs[128 * 32];

  const int z = blockIdx.z;
  const unsigned short* A = Xb + (size_t)z * M_TOT * E_DIM;
  const float* bias = (z == 0) ? bq : (z == 1) ? bk : bv;
  const unsigned short* W = WtAll + (size_t)z * E_DIM * E_DIM;
  unsigned short* out = outQKV + (size_t)z * M_TOT * E_DIM;
  const float scale = (z == 0) ? Q_SCALE : 1.0f;

  const int tid = threadIdx.x;
  const int lane = tid & 63, wv = tid >> 6;
  const int m15 = lane & 15, quad = lane >> 4;
  const int wm = (wv & 1) * 64, wn = (wv >> 1) * 64;
  const int m0 = blockIdx.x * 128, n0 = blockIdx.y * 128;

  floatx4 acc[4][4] = {};
  const int srow = lane >> 2, scol = (lane & 3) * 8;

  for (int k0 = 0; k0 < E_DIM; k0 += 32) {
    for (int cc = 0; cc < 2; cc++) {
      int c = wv * 2 + cc;
      gload_lds16(&A[(size_t)(m0 + c * 16 + srow) * E_DIM + k0 + scol], &As[c * 512]);
      gload_lds16(&W[(size_t)(n0 + c * 16 + srow) * E_DIM + k0 + scol], &Bs[c * 512]);
    }
    __syncthreads();
    bf16x8 af[4], bfr[4];
    for (int i = 0; i < 4; i++)
      af[i] = *reinterpret_cast<const bf16x8*>(&As[(wm + i * 16 + m15) * 32 + quad * 8]);
    for (int j = 0; j < 4; j++)
      bfr[j] = *reinterpret_cast<const bf16x8*>(&Bs[(wn + j * 16 + m15) * 32 + quad * 8]);
    for (int i = 0; i < 4; i++)
      for (int j = 0; j < 4; j++)
        acc[i][j] = __builtin_amdgcn_mfma_f32_16x16x32_bf16(af[i], bfr[j], acc[i][j], 0, 0, 0);
    __syncthreads();
  }

  for (int i = 0; i < 4; i++)
    for (int j = 0; j < 4; j++) {
      int gn = n0 + wn + j * 16 + m15;
      int h = gn >> 6, d = gn & 63;
      float bso = bias[gn];
      for (int r = 0; r < 4; r++) {
        int gm = m0 + wm + i * 16 + quad * 4 + r;
        int bb = gm >> 11, tt = gm & 2047;
        float v = (acc[i][j][r] + bso) * scale;
        out[(((size_t)bb * N_H + h) * T_DIM + tt) * H_D + d] = f32_to_bf16(v);
      }
    }
}

// ---- V transpose: VT[b][h][d][t] = QKV_v[b][h][t][d] ----
__global__ __launch_bounds__(256) void transpose_v(const unsigned short* __restrict__ Vg_all,
                                                   unsigned short* __restrict__ VT) {
  __shared__ unsigned short tile[64 * 72];
  const int t0 = blockIdx.x * 64, h = blockIdx.y, bb = blockIdx.z;
  const unsigned short* Vg = Vg_all + (((size_t)bb * N_H + h) * T_DIM) * H_D;
  unsigned short* VTh = VT + (((size_t)bb * N_H + h) * H_D) * T_DIM;
  const int tid = threadIdx.x;
  const int tloc = tid & 63, d0 = (tid >> 6) * 16;

  short8 r0 = *reinterpret_cast<const short8*>(&Vg[(size_t)(t0 + tloc) * H_D + d0]);
  short8 r1 = *reinterpret_cast<const short8*>(&Vg[(size_t)(t0 + tloc) * H_D + d0 + 8]);
#pragma unroll
  for (int j = 0; j < 8; j++) {
    tile[(d0 + j) * 72 + tloc] = (unsigned short)r0[j];
    tile[(d0 + 8 + j) * 72 + tloc] = (unsigned short)r1[j];
  }
  __syncthreads();
  const int d = tid >> 2, ts = (tid & 3) * 16;
  short8 w0 = *reinterpret_cast<const short8*>(&tile[d * 72 + ts]);
  short8 w1 = *reinterpret_cast<const short8*>(&tile[d * 72 + ts + 8]);
  *reinterpret_cast<short8*>(&VTh[(size_t)d * T_DIM + t0 + ts]) = w0;
  *reinterpret_cast<short8*>(&VTh[(size_t)d * T_DIM + t0 + ts + 8]) = w1;
}

// ---- flash attention: swapped-QK 32x32 MFMA, in-register P (cvt_pk + permlane32_swap),
//      XOR-swizzled K/V LDS staged via global_load_lds with pre-swizzled source,
//      counted-vmcnt double buffer. 2 waves/block, 32 q-rows per wave. ----
__global__ __launch_bounds__(128) void attn(const unsigned short* __restrict__ QKV,
                                            const unsigned short* __restrict__ VT,
                                            unsigned short* __restrict__ ctx) {
  // K tile [key][d], V tile [d][key]; rows 128B; 16B slot s holds global slot s^(row&7)
  __shared__ unsigned short Ks[2][64 * 64];
  __shared__ unsigned short Vs[2][64 * 64];

  const int qt = blockIdx.x, h = blockIdx.y, bb = blockIdx.z;
  const size_t headoff = (((size_t)bb * N_H + h) * T_DIM) * H_D;
  const unsigned short* Qg = QKV + headoff;
  const unsigned short* Kg = QKV + (size_t)M_TOT * E_DIM + headoff;
  const unsigned short* VTg = VT + (((size_t)bb * N_H + h) * H_D) * T_DIM;

  const int tid = threadIdx.x;
  const int lane = tid & 63, wv = tid >> 6;
  const int l31 = lane & 31, hi = lane >> 5, l7 = lane & 7;
  const int q0 = qt * 64 + wv * 32;

  // staging source (pre-swizzled so linear global_load_lds dest == swizzled layout)
  const int srow = lane >> 3;           // row within each 8-row group == row&7
  const int sslot = (lane & 7) ^ srow;  // swizzled 16B slot
  const unsigned short* gK = Kg + (size_t)srow * H_D + sslot * 8;     // + (kt*64 + i*8)*H_D
  const unsigned short* gV = VTg + (size_t)srow * T_DIM + sslot * 8;  // + i*8*T_DIM + kt*64

  // Q fragments (B-operand): lane holds Q[q0+l31][c*16 + hi*8 .. +7]
  bf16x8 aq[4];
#pragma unroll
  for (int c = 0; c < 4; c++)
    aq[c] = *reinterpret_cast<const bf16x8*>(&Qg[(size_t)(q0 + l31) * H_D + c * 16 + hi * 8]);

  // prologue: stage tiles 0 and 1 (wave0 -> K, wave1 -> V; 8 loads each per tile)
#pragma unroll
  for (int i = 0; i < 8; i++) {
    if (wv == 0) gload_lds16(gK + (size_t)(i * 8) * H_D, &Ks[0][i * 512]);
    else         gload_lds16(gV + (size_t)(i * 8) * T_DIM, &Vs[0][i * 512]);
  }
#pragma unroll
  for (int i = 0; i < 8; i++) {
    if (wv == 0) gload_lds16(gK + (size_t)(64 + i * 8) * H_D, &Ks[1][i * 512]);
    else         gload_lds16(gV + (size_t)(i * 8) * T_DIM + 64, &Vs[1][i * 512]);
  }
  asm volatile("s_waitcnt vmcnt(0)" ::: "memory");
  lds_barrier();

  f32x16 o0 = {}, o1 = {};
  float lacc = 0.f;

  for (int kt = 0; kt < 32; ++kt) {
    const unsigned short* kb = Ks[kt & 1];
    const unsigned short* vb = Vs[kt & 1];

    // ---- QK^T (swapped): S^T[key][q] for two 32-key subtiles ----
    f32x16 s0 = {}, s1 = {};
#pragma unroll
    for (int c = 0; c < 4; c++) {
      const int slot = ((c << 1) | hi) ^ l7;
      bf16x8 k0 = *reinterpret_cast<const bf16x8*>(&kb[l31 * 64 + slot * 8]);
      bf16x8 k1 = *reinterpret_cast<const bf16x8*>(&kb[(32 + l31) * 64 + slot * 8]);
      s0 = __builtin_amdgcn_mfma_f32_32x32x16_bf16(k0, aq[c], s0, 0, 0, 0);
      s1 = __builtin_amdgcn_mfma_f32_32x32x16_bf16(k1, aq[c], s1, 0, 0, 0);
    }

    // ---- softmax (no-max): p = exp2(s); row-sum fully in-register ----
#pragma unroll
    for (int i = 0; i < 16; i++) { s0[i] = EXP2F(s0[i]); s1[i] = EXP2F(s1[i]); }
    float ps = 0.f;
#pragma unroll
    for (int i = 0; i < 16; i++) ps += s0[i] + s1[i];
    lacc += ps;

    // ---- pack P -> PV A-fragments (in-register, 8 cvt_pk + 4 permlane per subtile) ----
    // perml32_swap(low_pairs, high_pairs): D-high <-> S-low exchange gives
    // element j <-> key base + hi*8 + j exactly (verified per-element, R1 post-mortem)
    bf16x8 pa0[2], pa1[2];
#pragma unroll
    for (int cc = 0; cc < 2; cc++) {
      {
        unsigned int x0 = cvtpk_bf16(s0[8 * cc + 0], s0[8 * cc + 1]);
        unsigned int x1 = cvtpk_bf16(s0[8 * cc + 2], s0[8 * cc + 3]);
        unsigned int y0 = cvtpk_bf16(s0[8 * cc + 4], s0[8 * cc + 5]);
        unsigned int y1 = cvtpk_bf16(s0[8 * cc + 6], s0[8 * cc + 7]);
        perml32_swap(x0, y0);
        perml32_swap(x1, y1);
        uint4v u; u[0] = x0; u[1] = x1; u[2] = y0; u[3] = y1;
        pa0[cc] = __builtin_bit_cast(bf16x8, u);
      }
      {
        unsigned int x0 = cvtpk_bf16(s1[8 * cc + 0], s1[8 * cc + 1]);
        unsigned int x1 = cvtpk_bf16(s1[8 * cc + 2], s1[8 * cc + 3]);
        unsigned int y0 = cvtpk_bf16(s1[8 * cc + 4], s1[8 * cc + 5]);
        unsigned int y1 = cvtpk_bf16(s1[8 * cc + 6], s1[8 * cc + 7]);
        perml32_swap(x0, y0);
        perml32_swap(x1, y1);
        uint4v u; u[0] = x0; u[1] = x1; u[2] = y0; u[3] = y1;
        pa1[cc] = __builtin_bit_cast(bf16x8, u);
      }
    }

    // ---- PV: o[q][d] += P * V   (B-frags from swizzled VT tile) ----
#pragma unroll
    for (int cc = 0; cc < 2; cc++) {
      const int sl0 = ((cc << 1) | hi) ^ l7;        // sub0 keys
      const int sl1 = (4 + (cc << 1) + hi) ^ l7;    // sub1 keys
      bf16x8 v00 = *reinterpret_cast<const bf16x8*>(&vb[l31 * 64 + sl0 * 8]);         // sub0, d 0..31
      bf16x8 v01 = *reinterpret_cast<const bf16x8*>(&vb[(32 + l31) * 64 + sl0 * 8]);  // sub0, d 32..63
      bf16x8 v10 = *reinterpret_cast<const bf16x8*>(&vb[l31 * 64 + sl1 * 8]);         // sub1, d 0..31
      bf16x8 v11 = *reinterpret_cast<const bf16x8*>(&vb[(32 + l31) * 64 + sl1 * 8]);  // sub1, d 32..63
      o0 = __builtin_amdgcn_mfma_f32_32x32x16_bf16(pa0[cc], v00, o0, 0, 0, 0);
      o1 = __builtin_amdgcn_mfma_f32_32x32x16_bf16(pa0[cc], v01, o1, 0, 0, 0);
      o0 = __builtin_amdgcn_mfma_f32_32x32x16_bf16(pa1[cc], v10, o0, 0, 0, 0);
      o1 = __builtin_amdgcn_mfma_f32_32x32x16_bf16(pa1[cc], v11, o1, 0, 0, 0);
    }

    if (kt == 31) break;
    lds_barrier();  // all waves done reading buf[kt&1]
    if (kt < 30) {
      const int nt = kt + 2;
#pragma unroll
      for (int i = 0; i < 8; i++) {
        if (wv == 0) gload_lds16(gK + (size_t)(nt * 64 + i * 8) * H_D, &Ks[kt & 1][i * 512]);
        else         gload_lds16(gV + (size_t)(i * 8) * T_DIM + nt * 64, &Vs[kt & 1][i * 512]);
      }
      asm volatile("s_waitcnt vmcnt(8)" ::: "memory");  // tile kt+1 landed; kt+2 stays in flight
    } else {
      asm volatile("s_waitcnt vmcnt(0)" ::: "memory");  // drain final tile
    }
    lds_barrier();  // tile kt+1 visible to both waves
  }

  // ---- epilogue: combine halves of l, normalize, store ----
  float ltot = lacc + __shfl_xor(lacc, 32, 64);
  float rl = RCPF(ltot);
  const size_t obase = ((size_t)bb * T_DIM + q0) * E_DIM + (size_t)h * H_D;
#pragma unroll
  for (int r = 0; r < 16; r++) {
    const int qrow = (r & 3) + 8 * (r >> 2) + 4 * hi;
    float rq = __shfl(rl, qrow, 64);
    ctx[obase + (size_t)qrow * E_DIM + l31]      = f32_to_bf16(o0[r] * rq);
    ctx[obase + (size_t)qrow * E_DIM + 32 + l31] = f32_to_bf16(o1[r] * rq);
  }
}

// ---- output projection: out = ctx @ Wo + bo (fp32) ----
__global__ __launch_bounds__(256) void gemm_out(const unsigned short* __restrict__ Actx,
                                                const unsigned short* __restrict__ Wt,
                                                const float* __restrict__ bias,
                                                float* __restrict__ out) {
  __shared__ unsigned short As[64 * 32];
  __shared__ unsigned short Bs[128 * 32];

  const int tid = threadIdx.x;
  const int lane = tid & 63, wv = tid >> 6;
  const int m15 = lane & 15, quad = lane >> 4;
  const int wm = (wv & 1) * 32, wn = (wv >> 1) * 64;
  const int m0 = blockIdx.x * 64, n0 = blockIdx.y * 128;

  floatx4 acc[2][4] = {};
  const int srow = lane >> 2, scol = (lane & 3) * 8;

  for (int k0 = 0; k0 < E_DIM; k0 += 32) {
    gload_lds16(&Actx[(size_t)(m0 + wv * 16 + srow) * E_DIM + k0 + scol], &As[wv * 512]);
    for (int cc = 0; cc < 2; cc++) {
      int c = wv * 2 + cc;
      gload_lds16(&Wt[(size_t)(n0 + c * 16 + srow) * E_DIM + k0 + scol], &Bs[c * 512]);
    }
    __syncthreads();
    bf16x8 af[2], bfr[4];
    for (int i = 0; i < 2; i++)
      af[i] = *reinterpret_cast<const bf16x8*>(&As[(wm + i * 16 + m15) * 32 + quad * 8]);
    for (int j = 0; j < 4; j++)
      bfr[j] = *reinterpret_cast<const bf16x8*>(&Bs[(wn + j * 16 + m15) * 32 + quad * 8]);
    for (int i = 0; i < 2; i++)
      for (int j = 0; j < 4; j++)
        acc[i][j] = __builtin_amdgcn_mfma_f32_16x16x32_bf16(af[i], bfr[j], acc[i][j], 0, 0, 0);
    __syncthreads();
  }

  for (int i = 0; i < 2; i++)
    for (int j = 0; j < 4; j++) {
      int gn = n0 + wn + j * 16 + m15;
      float bso = bias[gn];
      for (int r = 0; r < 4; r++) {
        int gm = m0 + wm + i * 16 + quad * 4 + r;
        out[(size_t)gm * E_DIM + gn] = acc[i][j][r] + bso;
      }
    }
}

extern "C" void kernel_launch(void* const* d_in, const int* in_sizes, int n_in,
                              void* d_out, int out_size, void* d_ws, size_t ws_size,
                              hipStream_t stream) {
  const float* query  = (const float*)d_in[0];
  const float* key_in = (const float*)d_in[1];
  const float* value  = (const float*)d_in[2];
  const float* Wq = (const float*)d_in[3];
  const float* bq = (const float*)d_in[4];
  const float* Wk = (const float*)d_in[5];
  const float* bk = (const float*)d_in[6];
  const float* Wv = (const float*)d_in[7];
  const float* bv = (const float*)d_in[8];
  const float* Wo = (const float*)d_in[9];
  const float* bo = (const float*)d_in[10];
  float* out = (float*)d_out;

  // ws layout (bf16): Wt[4][768][768] | Xb[3][4096][768] | QKV[3][4096][768] | VT[2][12][64][2048] | ctx[4096][768]
  unsigned short* ws  = (unsigned short*)d_ws;
  unsigned short* Wt  = ws;
  unsigned short* Xb  = Wt + (size_t)4 * E_DIM * E_DIM;
  unsigned short* QKV = Xb + (size_t)3 * M_TOT * E_DIM;
  unsigned short* VT  = QKV + (size_t)3 * M_TOT * E_DIM;
  unsigned short* ctx = VT + (size_t)N_B * N_H * H_D * T_DIM;

  dim3 tb(256);
  convert_x<<<dim3(M_TOT * E_DIM / 1024, 3), tb, 0, stream>>>(query, key_in, value, Xb);
  transpose_w4<<<dim3(24, 24, 4), tb, 0, stream>>>(Wq, Wk, Wv, Wo, Wt);

  gemm_qkv<<<dim3(32, 6, 3), tb, 0, stream>>>(Xb, Wt, bq, bk, bv, QKV);
  transpose_v<<<dim3(32, 12, 2), tb, 0, stream>>>(QKV + (size_t)2 * M_TOT * E_DIM, VT);
  attn<<<dim3(32, 12, 2), dim3(128), 0, stream>>>(QKV, VT, ctx);
  gemm_out<<<dim3(64, 6), tb, 0, stream>>>(ctx, Wt + (size_t)3 * E_DIM * E_DIM, bo, out);
  (void)in_sizes; (void)n_in; (void)out_size; (void)ws_size;
}

// Round 6
// 193.479 us; speedup vs baseline: 1.0611x; 1.0611x over previous
//
#include <hip/hip_runtime.h>
#include <math.h>

typedef __attribute__((ext_vector_type(4))) float  floatx4;
typedef __attribute__((ext_vector_type(16))) float f32x16;
typedef __attribute__((ext_vector_type(8))) short  short8;
typedef __attribute__((ext_vector_type(4))) short  short4v;
typedef __attribute__((ext_vector_type(8))) __bf16 bf16x8;
typedef __attribute__((ext_vector_type(4))) unsigned int uint4v;

#define E_DIM 768
#define T_DIM 2048
#define N_B   2
#define N_H   12
#define H_D   64
#define M_TOT 4096  /* N_B * T_DIM */

// 0.125 * log2(e): folded into Q so exp2() applies directly to QK^T output
#define Q_SCALE 0.1803368801111204f

#if __has_builtin(__builtin_amdgcn_exp2f)
#define EXP2F(x) __builtin_amdgcn_exp2f(x)
#else
#define EXP2F(x) exp2f(x)
#endif
#if __has_builtin(__builtin_amdgcn_rcpf)
#define RCPF(x) __builtin_amdgcn_rcpf(x)
#else
#define RCPF(x) (1.0f / (x))
#endif

__device__ __forceinline__ unsigned short f32_to_bf16(float f) {
  unsigned int u = __float_as_uint(f);
  u += 0x7fffu + ((u >> 16) & 1u);
  return (unsigned short)(u >> 16);
}

// barrier that waits LDS only (no vmcnt drain -> global prefetch stays in flight)
__device__ __forceinline__ void lds_barrier() {
  asm volatile("s_waitcnt lgkmcnt(0)\n\ts_barrier" ::: "memory");
}

__device__ __forceinline__ void gload_lds16(const unsigned short* g, unsigned short* l) {
  __builtin_amdgcn_global_load_lds(
      (const __attribute__((address_space(1))) unsigned int*)(const void*)g,
      (__attribute__((address_space(3))) unsigned int*)(void*)l, 16, 0, 0);
}

// v_cvt_pk_bf16_f32: low16 = bf16(lo), high16 = bf16(hi)  (no builtin on gfx950)
__device__ __forceinline__ unsigned int cvtpk_bf16(float lo, float hi) {
  unsigned int r;
  asm("v_cvt_pk_bf16_f32 %0, %1, %2" : "=v"(r) : "v"(lo), "v"(hi));
  return r;
}

// v_permlane32_swap_b32 D, S: exchanges the UPPER half of D with the LOWER half of S:
//   D[l>=32] <- S_old[l-32] ; S[l<32] <- D_old[l+32] ; D[l<32], S[l>=32] unchanged.
// Call as perml32_swap(low_pairs, high_pairs).
__device__ __forceinline__ void perml32_swap(unsigned int& a, unsigned int& b) {
  asm volatile("v_permlane32_swap_b32 %0, %1" : "+v"(a), "+v"(b));
}

// ---- input convert: Xb[z][m][k] = bf16(x[m][k]) ----
__global__ __launch_bounds__(256) void convert_x(const float* __restrict__ q,
                                                 const float* __restrict__ k,
                                                 const float* __restrict__ v,
                                                 unsigned short* __restrict__ Xb) {
  const int z = blockIdx.y;
  const float* src = (z == 0) ? q : (z == 1) ? k : v;
  size_t idx = ((size_t)blockIdx.x * 256 + threadIdx.x) * 4;
  float4 val = *reinterpret_cast<const float4*>(&src[idx]);
  short4v o;
  o[0] = (short)f32_to_bf16(val.x);
  o[1] = (short)f32_to_bf16(val.y);
  o[2] = (short)f32_to_bf16(val.z);
  o[3] = (short)f32_to_bf16(val.w);
  *reinterpret_cast<short4v*>(&Xb[(size_t)z * M_TOT * E_DIM + idx]) = o;
}

// ---- weight convert+transpose (all 4 weights, one launch): Wt[z][n][k] = bf16(W[z][k][n]) ----
__global__ __launch_bounds__(256) void transpose_w4(const float* __restrict__ W0,
                                                    const float* __restrict__ W1,
                                                    const float* __restrict__ W2,
                                                    const float* __restrict__ W3,
                                                    unsigned short* __restrict__ Wt) {
  __shared__ float tile[32][33];
  const int z = blockIdx.z;
  const float* W = (z == 0) ? W0 : (z == 1) ? W1 : (z == 2) ? W2 : W3;
  unsigned short* dst = Wt + (size_t)z * E_DIM * E_DIM;
  int k0 = blockIdx.x * 32, n0 = blockIdx.y * 32;
  int tx = threadIdx.x & 31, ty = threadIdx.x >> 5;
  for (int i = 0; i < 4; i++)
    tile[ty + i * 8][tx] = W[(size_t)(k0 + ty + i * 8) * E_DIM + n0 + tx];
  __syncthreads();
  for (int i = 0; i < 4; i++)
    dst[(size_t)(n0 + ty + i * 8) * E_DIM + k0 + tx] = f32_to_bf16(tile[tx][ty + i * 8]);
}

// ---- QKV projection (m97-style global_load_lds staging) ----
__global__ __launch_bounds__(256) void gemm_qkv(const unsigned short* __restrict__ Xb,
                                                const unsigned short* __restrict__ WtAll,
                                                const float* __restrict__ bq,
                                                const float* __restrict__ bk,
                                                const float* __restrict__ bv,
                                                unsigned short* __restrict__ outQKV) {
  __shared__ unsigned short As[128 * 32];
  __shared__ unsigned short Bs[128 * 32];

  const int z = blockIdx.z;
  const unsigned short* A = Xb + (size_t)z * M_TOT * E_DIM;
  const float* bias = (z == 0) ? bq : (z == 1) ? bk : bv;
  const unsigned short* W = WtAll + (size_t)z * E_DIM * E_DIM;
  unsigned short* out = outQKV + (size_t)z * M_TOT * E_DIM;
  const float scale = (z == 0) ? Q_SCALE : 1.0f;

  const int tid = threadIdx.x;
  const int lane = tid & 63, wv = tid >> 6;
  const int m15 = lane & 15, quad = lane >> 4;
  const int wm = (wv & 1) * 64, wn = (wv >> 1) * 64;
  const int m0 = blockIdx.x * 128, n0 = blockIdx.y * 128;

  floatx4 acc[4][4] = {};
  const int srow = lane >> 2, scol = (lane & 3) * 8;

  for (int k0 = 0; k0 < E_DIM; k0 += 32) {
    for (int cc = 0; cc < 2; cc++) {
      int c = wv * 2 + cc;
      gload_lds16(&A[(size_t)(m0 + c * 16 + srow) * E_DIM + k0 + scol], &As[c * 512]);
      gload_lds16(&W[(size_t)(n0 + c * 16 + srow) * E_DIM + k0 + scol], &Bs[c * 512]);
    }
    __syncthreads();
    bf16x8 af[4], bfr[4];
    for (int i = 0; i < 4; i++)
      af[i] = *reinterpret_cast<const bf16x8*>(&As[(wm + i * 16 + m15) * 32 + quad * 8]);
    for (int j = 0; j < 4; j++)
      bfr[j] = *reinterpret_cast<const bf16x8*>(&Bs[(wn + j * 16 + m15) * 32 + quad * 8]);
    for (int i = 0; i < 4; i++)
      for (int j = 0; j < 4; j++)
        acc[i][j] = __builtin_amdgcn_mfma_f32_16x16x32_bf16(af[i], bfr[j], acc[i][j], 0, 0, 0);
    __syncthreads();
  }

  for (int i = 0; i < 4; i++)
    for (int j = 0; j < 4; j++) {
      int gn = n0 + wn + j * 16 + m15;
      int h = gn >> 6, d = gn & 63;
      float bso = bias[gn];
      for (int r = 0; r < 4; r++) {
        int gm = m0 + wm + i * 16 + quad * 4 + r;
        int bb = gm >> 11, tt = gm & 2047;
        float v = (acc[i][j][r] + bso) * scale;
        out[(((size_t)bb * N_H + h) * T_DIM + tt) * H_D + d] = f32_to_bf16(v);
      }
    }
}

// ---- V transpose: VT[b][h][d][t] = QKV_v[b][h][t][d] ----
__global__ __launch_bounds__(256) void transpose_v(const unsigned short* __restrict__ Vg_all,
                                                   unsigned short* __restrict__ VT) {
  __shared__ unsigned short tile[64 * 72];
  const int t0 = blockIdx.x * 64, h = blockIdx.y, bb = blockIdx.z;
  const unsigned short* Vg = Vg_all + (((size_t)bb * N_H + h) * T_DIM) * H_D;
  unsigned short* VTh = VT + (((size_t)bb * N_H + h) * H_D) * T_DIM;
  const int tid = threadIdx.x;
  const int tloc = tid & 63, d0 = (tid >> 6) * 16;

  short8 r0 = *reinterpret_cast<const short8*>(&Vg[(size_t)(t0 + tloc) * H_D + d0]);
  short8 r1 = *reinterpret_cast<const short8*>(&Vg[(size_t)(t0 + tloc) * H_D + d0 + 8]);
#pragma unroll
  for (int j = 0; j < 8; j++) {
    tile[(d0 + j) * 72 + tloc] = (unsigned short)r0[j];
    tile[(d0 + 8 + j) * 72 + tloc] = (unsigned short)r1[j];
  }
  __syncthreads();
  const int d = tid >> 2, ts = (tid & 3) * 16;
  short8 w0 = *reinterpret_cast<const short8*>(&tile[d * 72 + ts]);
  short8 w1 = *reinterpret_cast<const short8*>(&tile[d * 72 + ts + 8]);
  *reinterpret_cast<short8*>(&VTh[(size_t)d * T_DIM + t0 + ts]) = w0;
  *reinterpret_cast<short8*>(&VTh[(size_t)d * T_DIM + t0 + ts + 8]) = w1;
}

// ---- flash attention: swapped-QK 32x32 MFMA, in-register P (cvt_pk + permlane32_swap),
//      lagged-PV software pipeline: iter kt issues QK(kt)+PV(kt-1) back-to-back (16
//      independent MFMAs), then barrier+stage-issue, then pack(kt) VALU overlapping the
//      MFMA drain and load flight. K staged 2-ahead, V 1-ahead; both depth-2 (32 KiB). ----
__global__ __launch_bounds__(128) void attn(const unsigned short* __restrict__ QKV,
                                            const unsigned short* __restrict__ VT,
                                            unsigned short* __restrict__ ctx) {
  // K tile [key][d], V tile [d][key]; rows 128B; 16B slot s holds global slot s^(row&7)
  __shared__ unsigned short Ks[2][64 * 64];
  __shared__ unsigned short Vs[2][64 * 64];

  const int qt = blockIdx.x, h = blockIdx.y, bb = blockIdx.z;
  const size_t headoff = (((size_t)bb * N_H + h) * T_DIM) * H_D;
  const unsigned short* Qg = QKV + headoff;
  const unsigned short* Kg = QKV + (size_t)M_TOT * E_DIM + headoff;
  const unsigned short* VTg = VT + (((size_t)bb * N_H + h) * H_D) * T_DIM;

  const int tid = threadIdx.x;
  const int lane = tid & 63, wv = tid >> 6;
  const int l31 = lane & 31, hi = lane >> 5, l7 = lane & 7;
  const int q0 = qt * 64 + wv * 32;

  // staging source (pre-swizzled so linear global_load_lds dest == swizzled layout)
  const int srow = lane >> 3;           // row within each 8-row group == row&7
  const int sslot = (lane & 7) ^ srow;  // swizzled 16B slot
  const unsigned short* gK = Kg + (size_t)srow * H_D + sslot * 8;     // + (kt*64 + i*8)*H_D
  const unsigned short* gV = VTg + (size_t)srow * T_DIM + sslot * 8;  // + i*8*T_DIM + kt*64

  // Q fragments (B-operand): lane holds Q[q0+l31][c*16 + hi*8 .. +7]
  bf16x8 aq[4];
#pragma unroll
  for (int c = 0; c < 4; c++)
    aq[c] = *reinterpret_cast<const bf16x8*>(&Qg[(size_t)(q0 + l31) * H_D + c * 16 + hi * 8]);

  // prologue: wave0 stages K0->Ks[0], K1->Ks[1]; wave1 stages V0->Vs[0]
#pragma unroll
  for (int i = 0; i < 8; i++) {
    if (wv == 0) gload_lds16(gK + (size_t)(i * 8) * H_D, &Ks[0][i * 512]);
    else         gload_lds16(gV + (size_t)(i * 8) * T_DIM, &Vs[0][i * 512]);
  }
  if (wv == 0) {
#pragma unroll
    for (int i = 0; i < 8; i++)
      gload_lds16(gK + (size_t)(64 + i * 8) * H_D, &Ks[1][i * 512]);
  }
  asm volatile("s_waitcnt vmcnt(0)" ::: "memory");
  lds_barrier();

  f32x16 o0 = {}, o1 = {};
  float lacc = 0.f;
  bf16x8 pa0[2], pa1[2];  // P fragments of the PREVIOUS tile (pipeline register)

  // ---- helpers ----
  auto QK = [&](const unsigned short* kb, f32x16& s0, f32x16& s1) {
#pragma unroll
    for (int c = 0; c < 4; c++) {
      const int slot = ((c << 1) | hi) ^ l7;
      bf16x8 k0 = *reinterpret_cast<const bf16x8*>(&kb[l31 * 64 + slot * 8]);
      bf16x8 k1 = *reinterpret_cast<const bf16x8*>(&kb[(32 + l31) * 64 + slot * 8]);
      s0 = __builtin_amdgcn_mfma_f32_32x32x16_bf16(k0, aq[c], s0, 0, 0, 0);
      s1 = __builtin_amdgcn_mfma_f32_32x32x16_bf16(k1, aq[c], s1, 0, 0, 0);
    }
  };
  auto PV = [&](const unsigned short* vb) {
#pragma unroll
    for (int cc = 0; cc < 2; cc++) {
      const int sl0 = ((cc << 1) | hi) ^ l7;        // sub0 keys
      const int sl1 = (4 + (cc << 1) + hi) ^ l7;    // sub1 keys
      bf16x8 v00 = *reinterpret_cast<const bf16x8*>(&vb[l31 * 64 + sl0 * 8]);
      bf16x8 v01 = *reinterpret_cast<const bf16x8*>(&vb[(32 + l31) * 64 + sl0 * 8]);
      bf16x8 v10 = *reinterpret_cast<const bf16x8*>(&vb[l31 * 64 + sl1 * 8]);
      bf16x8 v11 = *reinterpret_cast<const bf16x8*>(&vb[(32 + l31) * 64 + sl1 * 8]);
      o0 = __builtin_amdgcn_mfma_f32_32x32x16_bf16(pa0[cc], v00, o0, 0, 0, 0);
      o1 = __builtin_amdgcn_mfma_f32_32x32x16_bf16(pa0[cc], v01, o1, 0, 0, 0);
      o0 = __builtin_amdgcn_mfma_f32_32x32x16_bf16(pa1[cc], v10, o0, 0, 0, 0);
      o1 = __builtin_amdgcn_mfma_f32_32x32x16_bf16(pa1[cc], v11, o1, 0, 0, 0);
    }
  };
  auto PACK = [&](f32x16& s0, f32x16& s1) {
#pragma unroll
    for (int i = 0; i < 16; i++) { s0[i] = EXP2F(s0[i]); s1[i] = EXP2F(s1[i]); }
    float a0 = 0.f, a1 = 0.f, a2 = 0.f, a3 = 0.f;  // 4-way tree: short dep chains
#pragma unroll
    for (int i = 0; i < 16; i += 4) {
      a0 += s0[i]; a1 += s0[i + 1]; a2 += s0[i + 2]; a3 += s0[i + 3];
      a0 += s1[i]; a1 += s1[i + 1]; a2 += s1[i + 2]; a3 += s1[i + 3];
    }
    lacc += (a0 + a1) + (a2 + a3);
    // perml32_swap(low_pairs, high_pairs): element j <-> key base + hi*8 + j (R1 derivation)
#pragma unroll
    for (int cc = 0; cc < 2; cc++) {
      {
        unsigned int x0 = cvtpk_bf16(s0[8 * cc + 0], s0[8 * cc + 1]);
        unsigned int x1 = cvtpk_bf16(s0[8 * cc + 2], s0[8 * cc + 3]);
        unsigned int y0 = cvtpk_bf16(s0[8 * cc + 4], s0[8 * cc + 5]);
        unsigned int y1 = cvtpk_bf16(s0[8 * cc + 6], s0[8 * cc + 7]);
        perml32_swap(x0, y0);
        perml32_swap(x1, y1);
        uint4v u; u[0] = x0; u[1] = x1; u[2] = y0; u[3] = y1;
        pa0[cc] = __builtin_bit_cast(bf16x8, u);
      }
      {
        unsigned int x0 = cvtpk_bf16(s1[8 * cc + 0], s1[8 * cc + 1]);
        unsigned int x1 = cvtpk_bf16(s1[8 * cc + 2], s1[8 * cc + 3]);
        unsigned int y0 = cvtpk_bf16(s1[8 * cc + 4], s1[8 * cc + 5]);
        unsigned int y1 = cvtpk_bf16(s1[8 * cc + 6], s1[8 * cc + 7]);
        perml32_swap(x0, y0);
        perml32_swap(x1, y1);
        uint4v u; u[0] = x0; u[1] = x1; u[2] = y0; u[3] = y1;
        pa1[cc] = __builtin_bit_cast(bf16x8, u);
      }
    }
  };

  // ---- iter 0 (no PV yet): QK(0) -> pack -> pa; stage K2->Ks[0], V1->Vs[1] ----
  {
    f32x16 s0 = {}, s1 = {};
    __builtin_amdgcn_s_setprio(1);
    QK(Ks[0], s0, s1);
    __builtin_amdgcn_s_setprio(0);
    lds_barrier();  // B1: all waves done reading Ks[0]
#pragma unroll
    for (int i = 0; i < 8; i++) {
      if (wv == 0) gload_lds16(gK + (size_t)(128 + i * 8) * H_D, &Ks[0][i * 512]);
      else         gload_lds16(gV + (size_t)(i * 8) * T_DIM + 64, &Vs[1][i * 512]);
    }
    PACK(s0, s1);
    asm volatile("s_waitcnt vmcnt(8)" ::: "memory");  // K1/V0 long landed; K2/V1 in flight
    lds_barrier();  // B2
  }

  // ---- main loop kt = 1..30: QK(kt) + PV(kt-1) || stage || pack(kt) ----
  for (int kt = 1; kt <= 30; ++kt) {
    f32x16 s0 = {}, s1 = {};
    __builtin_amdgcn_s_setprio(1);
    QK(Ks[kt & 1], s0, s1);       // reads K(kt)
    PV(Vs[(kt - 1) & 1]);         // reads V(kt-1), uses pa = P(kt-1); independent of QK
    __builtin_amdgcn_s_setprio(0);
    lds_barrier();  // B1: all waves done reading Ks[kt&1], Vs[(kt-1)&1]
    if (wv == 0) {
      if (kt < 30) {
        const int nt = kt + 2;    // K(kt+2) -> slot just freed by QK(kt)
#pragma unroll
        for (int i = 0; i < 8; i++)
          gload_lds16(gK + (size_t)(nt * 64 + i * 8) * H_D, &Ks[kt & 1][i * 512]);
      }
    } else {
      const int nt = kt + 1;      // V(kt+1) -> slot just freed by PV(kt-1)
#pragma unroll
      for (int i = 0; i < 8; i++)
        gload_lds16(gV + (size_t)(i * 8) * T_DIM + nt * 64, &Vs[nt & 1][i * 512]);
    }
    PACK(s0, s1);                 // VALU overlaps PV MFMA drain + load flight
    if (kt == 30) asm volatile("s_waitcnt vmcnt(0)" ::: "memory");  // drain K31,V30,V31
    else          asm volatile("s_waitcnt vmcnt(8)" ::: "memory");  // K(kt+1)/V(kt) landed
    lds_barrier();  // B2: staged tiles visible to both waves
  }

  // ---- iter 31: QK(31) + PV(30), pack(31), then PV(31) ----
  {
    f32x16 s0 = {}, s1 = {};
    __builtin_amdgcn_s_setprio(1);
    QK(Ks[1], s0, s1);            // K(31)
    PV(Vs[0]);                    // V(30)
    __builtin_amdgcn_s_setprio(0);
    PACK(s0, s1);
    __builtin_amdgcn_s_setprio(1);
    PV(Vs[1]);                    // V(31)
    __builtin_amdgcn_s_setprio(0);
  }

  // ---- epilogue: combine halves of l, normalize, store ----
  float ltot = lacc + __shfl_xor(lacc, 32, 64);
  float rl = RCPF(ltot);
  const size_t obase = ((size_t)bb * T_DIM + q0) * E_DIM + (size_t)h * H_D;
#pragma unroll
  for (int r = 0; r < 16; r++) {
    const int qrow = (r & 3) + 8 * (r >> 2) + 4 * hi;
    float rq = __shfl(rl, qrow, 64);
    ctx[obase + (size_t)qrow * E_DIM + l31]      = f32_to_bf16(o0[r] * rq);
    ctx[obase + (size_t)qrow * E_DIM + 32 + l31] = f32_to_bf16(o1[r] * rq);
  }
}

// ---- output projection: out = ctx @ Wo + bo (fp32) ----
__global__ __launch_bounds__(256) void gemm_out(const unsigned short* __restrict__ Actx,
                                                const unsigned short* __restrict__ Wt,
                                                const float* __restrict__ bias,
                                                float* __restrict__ out) {
  __shared__ unsigned short As[64 * 32];
  __shared__ unsigned short Bs[128 * 32];

  const int tid = threadIdx.x;
  const int lane = tid & 63, wv = tid >> 6;
  const int m15 = lane & 15, quad = lane >> 4;
  const int wm = (wv & 1) * 32, wn = (wv >> 1) * 64;
  const int m0 = blockIdx.x * 64, n0 = blockIdx.y * 128;

  floatx4 acc[2][4] = {};
  const int srow = lane >> 2, scol = (lane & 3) * 8;

  for (int k0 = 0; k0 < E_DIM; k0 += 32) {
    gload_lds16(&Actx[(size_t)(m0 + wv * 16 + srow) * E_DIM + k0 + scol], &As[wv * 512]);
    for (int cc = 0; cc < 2; cc++) {
      int c = wv * 2 + cc;
      gload_lds16(&Wt[(size_t)(n0 + c * 16 + srow) * E_DIM + k0 + scol], &Bs[c * 512]);
    }
    __syncthreads();
    bf16x8 af[2], bfr[4];
    for (int i = 0; i < 2; i++)
      af[i] = *reinterpret_cast<const bf16x8*>(&As[(wm + i * 16 + m15) * 32 + quad * 8]);
    for (int j = 0; j < 4; j++)
      bfr[j] = *reinterpret_cast<const bf16x8*>(&Bs[(wn + j * 16 + m15) * 32 + quad * 8]);
    for (int i = 0; i < 2; i++)
      for (int j = 0; j < 4; j++)
        acc[i][j] = __builtin_amdgcn_mfma_f32_16x16x32_bf16(af[i], bfr[j], acc[i][j], 0, 0, 0);
    __syncthreads();
  }

  for (int i = 0; i < 2; i++)
    for (int j = 0; j < 4; j++) {
      int gn = n0 + wn + j * 16 + m15;
      float bso = bias[gn];
      for (int r = 0; r < 4; r++) {
        int gm = m0 + wm + i * 16 + quad * 4 + r;
        out[(size_t)gm * E_DIM + gn] = acc[i][j][r] + bso;
      }
    }
}

extern "C" void kernel_launch(void* const* d_in, const int* in_sizes, int n_in,
                              void* d_out, int out_size, void* d_ws, size_t ws_size,
                              hipStream_t stream) {
  const float* query  = (const float*)d_in[0];
  const float* key_in = (const float*)d_in[1];
  const float* value  = (const float*)d_in[2];
  const float* Wq = (const float*)d_in[3];
  const float* bq = (const float*)d_in[4];
  const float* Wk = (const float*)d_in[5];
  const float* bk = (const float*)d_in[6];
  const float* Wv = (const float*)d_in[7];
  const float* bv = (const float*)d_in[8];
  const float* Wo = (const float*)d_in[9];
  const float* bo = (const float*)d_in[10];
  float* out = (float*)d_out;

  // ws layout (bf16): Wt[4][768][768] | Xb[3][4096][768] | QKV[3][4096][768] | VT[2][12][64][2048] | ctx[4096][768]
  unsigned short* ws  = (unsigned short*)d_ws;
  unsigned short* Wt  = ws;
  unsigned short* Xb  = Wt + (size_t)4 * E_DIM * E_DIM;
  unsigned short* QKV = Xb + (size_t)3 * M_TOT * E_DIM;
  unsigned short* VT  = QKV + (size_t)3 * M_TOT * E_DIM;
  unsigned short* ctx = VT + (size_t)N_B * N_H * H_D * T_DIM;

  dim3 tb(256);
  convert_x<<<dim3(M_TOT * E_DIM / 1024, 3), tb, 0, stream>>>(query, key_in, value, Xb);
  transpose_w4<<<dim3(24, 24, 4), tb, 0, stream>>>(Wq, Wk, Wv, Wo, Wt);

  gemm_qkv<<<dim3(32, 6, 3), tb, 0, stream>>>(Xb, Wt, bq, bk, bv, QKV);
  transpose_v<<<dim3(32, 12, 2), tb, 0, stream>>>(QKV + (size_t)2 * M_TOT * E_DIM, VT);
  attn<<<dim3(32, 12, 2), dim3(128), 0, stream>>>(QKV, VT, ctx);
  gemm_out<<<dim3(64, 6), tb, 0, stream>>>(ctx, Wt + (size_t)3 * E_DIM * E_DIM, bo, out);
  (void)in_sizes; (void)n_in; (void)out_size; (void)ws_size;
}